// Round 3
// baseline (822.776 us; speedup 1.0000x reference)
//
#include <hip/hip_runtime.h>

namespace {
constexpr int Bn = 8;
constexpr int Sn = 1024;
constexpr int Dn = 1024;
constexpr int Hn = 16;
constexpr int DPH = 64;       // Dn / Hn
constexpr int QB  = 64;       // q rows per block (16 per wave)
constexpr int KB  = 64;       // k cols per tile
constexpr int NT  = Sn / KB;  // 16 k-tiles
// fold 1/sqrt(dph) AND log2(e) into Q so softmax runs in exp2 domain
constexpr float QSCALE    = 0.125f * 1.44269504088896340736f;
constexpr float DROPSCALE = 1.0f / 0.9f;

typedef __attribute__((ext_vector_type(4))) float    f32x4;
typedef __attribute__((ext_vector_type(4))) int      i32x4;
typedef __attribute__((ext_vector_type(8))) _Float16 f16x8;
typedef __attribute__((ext_vector_type(4))) _Float16 f16x4;
}

__device__ __forceinline__ float exp2_fast(float x) {
    float r;
    asm("v_exp_f32 %0, %1" : "=v"(r) : "v"(x));
    return r;
}

__global__ __launch_bounds__(256)
void mha_fwd(const float* __restrict__ Q, const float* __restrict__ K,
             const float* __restrict__ V, const int* __restrict__ msk,
             const float* __restrict__ dmask, float* __restrict__ out)
{
    // +8 halves pad: rows 16B-aligned (144B stride)
    __shared__ __align__(16) _Float16 Kl[KB][DPH + 8];
    __shared__ __align__(16) _Float16 Vt[DPH][KB + 8];   // V transposed: [d][k]
    __shared__ __align__(16) _Float16 Pl[4][16][KB + 8]; // per-wave P strip [q][k]

    const int tid = threadIdx.x;
    const int w   = tid >> 6;    // wave id, owns q rows [16w, 16w+16)
    const int l   = tid & 63;
    const int c16 = l & 15;      // lane's q-row (frag row/col index)
    const int g   = l >> 4;      // lane group 0..3
    const int kg  = g << 3;      // frag k-chunk base

    const int bid = blockIdx.x;
    const int qt = bid & (Sn / QB - 1);
    const int h  = (bid >> 4) & (Hn - 1);
    const int b  = bid >> 8;
    const int qbase = qt * QB;
    const size_t hoff = (size_t)h * DPH;

    // ---- Q fragments: lane holds Q[qbase+16w+c16][kg..kg+7] and +32 (pre-scaled) ----
    f16x8 qf0, qf1;
    {
        const float* qp = Q + ((size_t)(b * Sn + qbase + w * 16 + c16)) * Dn + hoff;
        f32x4 a0 = *reinterpret_cast<const f32x4*>(qp + kg);
        f32x4 a1 = *reinterpret_cast<const f32x4*>(qp + kg + 4);
        f32x4 b0 = *reinterpret_cast<const f32x4*>(qp + 32 + kg);
        f32x4 b1 = *reinterpret_cast<const f32x4*>(qp + 32 + kg + 4);
        #pragma unroll
        for (int j = 0; j < 4; ++j) {
            qf0[j]     = (_Float16)(a0[j] * QSCALE);
            qf0[4 + j] = (_Float16)(a1[j] * QSCALE);
            qf1[j]     = (_Float16)(b0[j] * QSCALE);
            qf1[4 + j] = (_Float16)(b1[j] * QSCALE);
        }
    }

    // ---- staging state (T14 reg-staged K/V, 2-deep dm prefetch) ----
    f32x4 kreg[4], vreg[4];
    auto kv_load = [&](int kt) {
        const size_t rbase = (size_t)(b * Sn + kt * KB);
        #pragma unroll
        for (int i = 0; i < 4; ++i) {
            // K: rows 16w+4g+i, 16 lanes cover 64 consecutive floats (256B/row)
            kreg[i] = *reinterpret_cast<const f32x4*>(
                K + (rbase + 16 * w + 4 * g + i) * Dn + hoff + 4 * c16);
            // V: rows 4*c16+i, 4 g-lanes cover 64B per row
            vreg[i] = *reinterpret_cast<const f32x4*>(
                V + (rbase + 4 * c16 + i) * Dn + hoff + 16 * w + 4 * g);
        }
    };
    auto kv_store = [&]() {
        #pragma unroll
        for (int i = 0; i < 4; ++i) {   // K row-major, packed 8B, 2-way banks
            f16x4 kp;
            #pragma unroll
            for (int j = 0; j < 4; ++j) kp[j] = (_Float16)kreg[i][j];
            *reinterpret_cast<f16x4*>(&Kl[16 * w + 4 * g + i][4 * c16]) = kp;
        }
        #pragma unroll
        for (int j = 0; j < 4; ++j) {   // V 4x4 reg-transpose, packed 8B, 2-way banks
            f16x4 vp;
            #pragma unroll
            for (int i = 0; i < 4; ++i) vp[i] = (_Float16)vreg[i][j];
            *reinterpret_cast<f16x4*>(&Vt[16 * w + 4 * g + j][4 * c16]) = vp;
        }
    };

    f32x4 dmA[4], dmB[4];  // dropout tiles in flight (2-deep, covers HBM latency)
    const float* dm_base = dmask + ((size_t)(b * Hn + h)) * Sn * Sn
                         + (size_t)(qbase + 16 * w + c16) * Sn;
    auto dm_load = [&](int kt, f32x4* dst) {
        #pragma unroll
        for (int c = 0; c < 4; ++c)
            dst[c] = *reinterpret_cast<const f32x4*>(dm_base + (size_t)kt * KB + 16 * c + 4 * g);
    };

    // ---- prologue ----
    kv_load(0);
    dm_load(0, dmA);
    dm_load(1, dmB);

    f32x4 acc[4];
    #pragma unroll
    for (int dt = 0; dt < 4; ++dt) acc[dt] = (f32x4){0.f, 0.f, 0.f, 0.f};
    float m_r = -INFINITY;
    float l_r = 0.f;

    #pragma unroll 1
    for (int kt = 0; kt < NT; ++kt) {
        __syncthreads();   // previous tile's Kl/Vt reads done
        kv_store();        // regs (tile kt) -> LDS
        if (kt + 1 < NT) kv_load(kt + 1);   // issue next tile's loads now
        // key mask for CURRENT tile (L2-hot; latency hidden under staging+QK^T)
        i32x4 mi[4];
        #pragma unroll
        for (int c = 0; c < 4; ++c)
            mi[c] = *reinterpret_cast<const i32x4*>(msk + b * Sn + kt * KB + 16 * c + 4 * g);
        __syncthreads();

        // ---- QK^T swapped: sc[c] = S^T frag; lane: q=c16, k = 16c+4g+r ----
        f32x4 sc[4];
        #pragma unroll
        for (int c = 0; c < 4; ++c) {
            f16x8 kf0 = *reinterpret_cast<const f16x8*>(&Kl[c * 16 + c16][kg]);
            f16x8 kf1 = *reinterpret_cast<const f16x8*>(&Kl[c * 16 + c16][32 + kg]);
            f32x4 z = {0.f, 0.f, 0.f, 0.f};
            z = __builtin_amdgcn_mfma_f32_16x16x32_f16(kf0, qf0, z, 0, 0, 0);
            z = __builtin_amdgcn_mfma_f32_16x16x32_f16(kf1, qf1, z, 0, 0, 0);
            sc[c] = z;
        }
        // ---- key mask: k masked -> -1e20 ----
        #pragma unroll
        for (int c = 0; c < 4; ++c) {
            #pragma unroll
            for (int r = 0; r < 4; ++r)
                sc[c][r] = (mi[c][r] != 0) ? sc[c][r] : -1e20f;
        }
        // ---- online softmax: lane-local row, only 2 shfl per reduce ----
        float tm = fmaxf(fmaxf(fmaxf(sc[0][0], sc[0][1]), fmaxf(sc[0][2], sc[0][3])),
                         fmaxf(fmaxf(sc[1][0], sc[1][1]), fmaxf(sc[1][2], sc[1][3])));
        tm = fmaxf(tm, fmaxf(fmaxf(fmaxf(sc[2][0], sc[2][1]), fmaxf(sc[2][2], sc[2][3])),
                             fmaxf(fmaxf(sc[3][0], sc[3][1]), fmaxf(sc[3][2], sc[3][3]))));
        tm = fmaxf(tm, __shfl_xor(tm, 16));
        tm = fmaxf(tm, __shfl_xor(tm, 32));
        float mn = fmaxf(m_r, tm);
        float al = exp2_fast(m_r - mn);   // 0 on first tile
        m_r = mn;
        float rs = 0.f;
        #pragma unroll
        for (int c = 0; c < 4; ++c) {
            #pragma unroll
            for (int r = 0; r < 4; ++r) {
                sc[c][r] = exp2_fast(sc[c][r] - mn);  // sc becomes p
                rs += sc[c][r];                       // denominator EXCLUDES dropout
            }
        }
        rs += __shfl_xor(rs, 16);
        rs += __shfl_xor(rs, 32);
        l_r = l_r * al + rs;
        #pragma unroll
        for (int dt = 0; dt < 4; ++dt) {
            #pragma unroll
            for (int r = 0; r < 4; ++r) acc[dt][r] *= al;
        }
        // ---- dropout on numerator, packed P^T write (8B, 2-way banks) ----
        const f32x4* dmv = (kt & 1) ? dmB : dmA;
        #pragma unroll
        for (int c = 0; c < 4; ++c) {
            f16x4 pw;
            #pragma unroll
            for (int r = 0; r < 4; ++r) pw[r] = (_Float16)(sc[c][r] * dmv[c][r]);
            *reinterpret_cast<f16x4*>(&Pl[w][c16][16 * c + 4 * g]) = pw;
        }
        if (kt + 2 < NT) dm_load(kt + 2, (kt & 1) ? dmB : dmA);  // 2-tile-ahead prefetch
        // ---- PV swapped: acc = O^T frag (wave-private Pl, no barrier) ----
        f16x8 pf0 = *reinterpret_cast<const f16x8*>(&Pl[w][c16][kg]);
        f16x8 pf1 = *reinterpret_cast<const f16x8*>(&Pl[w][c16][32 + kg]);
        #pragma unroll
        for (int dt = 0; dt < 4; ++dt) {
            f16x8 vf0 = *reinterpret_cast<const f16x8*>(&Vt[dt * 16 + c16][kg]);
            f16x8 vf1 = *reinterpret_cast<const f16x8*>(&Vt[dt * 16 + c16][32 + kg]);
            acc[dt] = __builtin_amdgcn_mfma_f32_16x16x32_f16(vf0, pf0, acc[dt], 0, 0, 0);
            acc[dt] = __builtin_amdgcn_mfma_f32_16x16x32_f16(vf1, pf1, acc[dt], 0, 0, 0);
        }
    }

    // ---- epilogue: lane-local l_r, coalesced float4 stores ----
    float inv = DROPSCALE / l_r;
    float* orow = out + ((size_t)(b * Sn + qbase + 16 * w + c16)) * Dn + hoff;
    #pragma unroll
    for (int dt = 0; dt < 4; ++dt) {
        f32x4 o4;
        #pragma unroll
        for (int r = 0; r < 4; ++r) o4[r] = acc[dt][r] * inv;
        *reinterpret_cast<f32x4*>(orow + dt * 16 + 4 * g) = o4;
    }
}

extern "C" void kernel_launch(void* const* d_in, const int* in_sizes, int n_in,
                              void* d_out, int out_size, void* d_ws, size_t ws_size,
                              hipStream_t stream)
{
    (void)in_sizes; (void)n_in; (void)out_size; (void)d_ws; (void)ws_size;
    const float* Q   = (const float*)d_in[0];
    const float* K   = (const float*)d_in[1];
    const float* V   = (const float*)d_in[2];
    const int*   msk = (const int*)d_in[3];
    const float* dm  = (const float*)d_in[4];
    float* o = (float*)d_out;

    dim3 grid(Bn * Hn * (Sn / QB));   // 2048 blocks
    dim3 block(256);                  // 4 waves
    mha_fwd<<<grid, block, 0, stream>>>(Q, K, V, msk, dm, o);
}

// Round 8
// 807.460 us; speedup vs baseline: 1.0190x; 1.0190x over previous
//
#include <hip/hip_runtime.h>

namespace {
constexpr int Bn = 8;
constexpr int Sn = 1024;
constexpr int Dn = 1024;
constexpr int Hn = 16;
constexpr int DPH = 64;       // Dn / Hn
constexpr int QB  = 64;       // q rows per block (16 per wave)
constexpr int KB  = 64;       // k cols per tile
constexpr int NT  = Sn / KB;  // 16 k-tiles
// fold 1/sqrt(dph) AND log2(e) into Q so softmax runs in exp2 domain
constexpr float QSCALE    = 0.125f * 1.44269504088896340736f;
constexpr float DROPSCALE = 1.0f / 0.9f;
constexpr float DEFER_THR = 8.0f;   // exp2-domain: P bounded by 2^8, fine in f16

typedef __attribute__((ext_vector_type(4))) float    f32x4;
typedef __attribute__((ext_vector_type(4))) int      i32x4;
typedef __attribute__((ext_vector_type(8))) _Float16 f16x8;
typedef __attribute__((ext_vector_type(4))) _Float16 f16x4;
}

__device__ __forceinline__ float exp2_fast(float x) {
    float r;
    asm("v_exp_f32 %0, %1" : "=v"(r) : "v"(x));
    return r;
}

__global__ __launch_bounds__(256)
void mha_fwd(const float* __restrict__ Q, const float* __restrict__ K,
             const float* __restrict__ V, const int* __restrict__ msk,
             const float* __restrict__ dmask, float* __restrict__ out)
{
    // +8 halves pad: rows 16B-aligned (144B stride), 2-way banks everywhere (free)
    __shared__ __align__(16) _Float16 Kl[KB][DPH + 8];
    __shared__ __align__(16) _Float16 Vt[DPH][KB + 8];   // V transposed: [d][k]
    __shared__ __align__(16) _Float16 Pl[4][16][KB + 8]; // per-wave P strip [q][k]
    __shared__ __align__(16) int      Ml[Sn];            // whole-row key mask (4 KB)

    const int tid = threadIdx.x;
    const int w   = tid >> 6;    // wave id, owns q rows [16w, 16w+16)
    const int l   = tid & 63;
    const int c16 = l & 15;      // lane's q-row (frag row/col index)
    const int g   = l >> 4;      // lane group 0..3
    const int kg  = g << 3;      // frag k-chunk base

    const int bid = blockIdx.x;
    const int qt = bid & (Sn / QB - 1);
    const int h  = (bid >> 4) & (Hn - 1);
    const int b  = bid >> 8;
    const int qbase = qt * QB;
    const size_t hoff = (size_t)h * DPH;

    // ---- stage whole key-mask row to LDS (removes mask from vmem chain) ----
    *reinterpret_cast<i32x4*>(&Ml[4 * tid]) =
        *reinterpret_cast<const i32x4*>(msk + b * Sn + 4 * tid);

    // ---- Q fragments: lane holds Q[qbase+16w+c16][kg..kg+7] and +32 (pre-scaled) ----
    f16x8 qf0, qf1;
    {
        const float* qp = Q + ((size_t)(b * Sn + qbase + w * 16 + c16)) * Dn + hoff;
        f32x4 a0 = *reinterpret_cast<const f32x4*>(qp + kg);
        f32x4 a1 = *reinterpret_cast<const f32x4*>(qp + kg + 4);
        f32x4 b0 = *reinterpret_cast<const f32x4*>(qp + 32 + kg);
        f32x4 b1 = *reinterpret_cast<const f32x4*>(qp + 32 + kg + 4);
        #pragma unroll
        for (int j = 0; j < 4; ++j) {
            qf0[j]     = (_Float16)(a0[j] * QSCALE);
            qf0[4 + j] = (_Float16)(a1[j] * QSCALE);
            qf1[j]     = (_Float16)(b0[j] * QSCALE);
            qf1[4 + j] = (_Float16)(b1[j] * QSCALE);
        }
    }

    // ---- staging state (T14 reg-staged K/V, 2-deep dm prefetch) ----
    f32x4 kreg[4], vreg[4];
    auto kv_load = [&](int kt) {
        const size_t rbase = (size_t)(b * Sn + kt * KB);
        #pragma unroll
        for (int i = 0; i < 4; ++i) {
            kreg[i] = *reinterpret_cast<const f32x4*>(
                K + (rbase + 16 * w + 4 * g + i) * Dn + hoff + 4 * c16);
            vreg[i] = *reinterpret_cast<const f32x4*>(
                V + (rbase + 4 * c16 + i) * Dn + hoff + 16 * w + 4 * g);
        }
    };
    auto kv_store = [&]() {
        #pragma unroll
        for (int i = 0; i < 4; ++i) {   // K row-major, packed 8B
            f16x4 kp;
            #pragma unroll
            for (int j = 0; j < 4; ++j) kp[j] = (_Float16)kreg[i][j];
            *reinterpret_cast<f16x4*>(&Kl[16 * w + 4 * g + i][4 * c16]) = kp;
        }
        #pragma unroll
        for (int j = 0; j < 4; ++j) {   // V 4x4 reg-transpose, packed 8B
            f16x4 vp;
            #pragma unroll
            for (int i = 0; i < 4; ++i) vp[i] = (_Float16)vreg[i][j];
            *reinterpret_cast<f16x4*>(&Vt[16 * w + 4 * g + j][4 * c16]) = vp;
        }
    };

    f32x4 dmA[4], dmB[4];  // dropout tiles in flight (2-deep)
    const float* dm_base = dmask + ((size_t)(b * Hn + h)) * Sn * Sn
                         + (size_t)(qbase + 16 * w + c16) * Sn;
    auto dm_load = [&](int kt, f32x4* dst) {
        #pragma unroll
        for (int c = 0; c < 4; ++c)
            dst[c] = *reinterpret_cast<const f32x4*>(dm_base + (size_t)kt * KB + 16 * c + 4 * g);
    };

    // ---- prologue ----
    kv_load(0);
    dm_load(0, dmA);
    dm_load(1, dmB);

    f32x4 acc[4];
    #pragma unroll
    for (int dt = 0; dt < 4; ++dt) acc[dt] = (f32x4){0.f, 0.f, 0.f, 0.f};
    float m_r = -INFINITY;
    float l_r = 0.f;

    #pragma unroll 1
    for (int kt = 0; kt < NT; ++kt) {
        __syncthreads();   // previous tile's Kl/Vt reads done (also covers Ml prologue)
        kv_store();        // regs (tile kt) -> LDS; consumes kreg/vreg w/ counted vmcnt
        if (kt + 1 < NT) kv_load(kt + 1);   // next tile stays in flight ALL iteration
        __syncthreads();

        // key mask from LDS (same-address broadcast across c16 lanes: conflict-free)
        i32x4 mi[4];
        #pragma unroll
        for (int c = 0; c < 4; ++c)
            mi[c] = *reinterpret_cast<const i32x4*>(&Ml[kt * KB + 16 * c + 4 * g]);

        // ---- QK^T swapped: lane owns q-row c16, k = 16c+4g+r ----
        f32x4 sc[4];
        __builtin_amdgcn_s_setprio(1);
        #pragma unroll
        for (int c = 0; c < 4; ++c) {
            f16x8 kf0 = *reinterpret_cast<const f16x8*>(&Kl[c * 16 + c16][kg]);
            f16x8 kf1 = *reinterpret_cast<const f16x8*>(&Kl[c * 16 + c16][32 + kg]);
            f32x4 z = {0.f, 0.f, 0.f, 0.f};
            z = __builtin_amdgcn_mfma_f32_16x16x32_f16(kf0, qf0, z, 0, 0, 0);
            z = __builtin_amdgcn_mfma_f32_16x16x32_f16(kf1, qf1, z, 0, 0, 0);
            sc[c] = z;
        }
        __builtin_amdgcn_s_setprio(0);
        // ---- key mask: k masked -> -1e20 ----
        #pragma unroll
        for (int c = 0; c < 4; ++c) {
            #pragma unroll
            for (int r = 0; r < 4; ++r)
                sc[c][r] = (mi[c][r] != 0) ? sc[c][r] : -1e20f;
        }
        // ---- online softmax, lane-local row, defer-max (T13) ----
        float tm = fmaxf(fmaxf(fmaxf(sc[0][0], sc[0][1]), fmaxf(sc[0][2], sc[0][3])),
                         fmaxf(fmaxf(sc[1][0], sc[1][1]), fmaxf(sc[1][2], sc[1][3])));
        tm = fmaxf(tm, fmaxf(fmaxf(fmaxf(sc[2][0], sc[2][1]), fmaxf(sc[2][2], sc[2][3])),
                             fmaxf(fmaxf(sc[3][0], sc[3][1]), fmaxf(sc[3][2], sc[3][3]))));
        tm = fmaxf(tm, __shfl_xor(tm, 16));
        tm = fmaxf(tm, __shfl_xor(tm, 32));
        const bool nogrow = __all(tm <= m_r + DEFER_THR);
        float al = 1.0f;
        if (!nogrow) {
            float mn = fmaxf(m_r, tm);
            al = exp2_fast(m_r - mn);   // 0 on first tile
            m_r = mn;
        }
        float rs = 0.f;
        #pragma unroll
        for (int c = 0; c < 4; ++c) {
            #pragma unroll
            for (int r = 0; r < 4; ++r) {
                sc[c][r] = exp2_fast(sc[c][r] - m_r);  // sc becomes p (<= 2^THR)
                rs += sc[c][r];                        // denominator EXCLUDES dropout
            }
        }
        rs += __shfl_xor(rs, 16);
        rs += __shfl_xor(rs, 32);
        if (nogrow) {
            l_r += rs;
        } else {
            l_r = l_r * al + rs;
            #pragma unroll
            for (int dt = 0; dt < 4; ++dt) {
                #pragma unroll
                for (int r = 0; r < 4; ++r) acc[dt][r] *= al;
            }
        }
        // ---- dropout on numerator, packed P^T write (8B) ----
        const f32x4* dmv = (kt & 1) ? dmB : dmA;
        #pragma unroll
        for (int c = 0; c < 4; ++c) {
            f16x4 pw;
            #pragma unroll
            for (int r = 0; r < 4; ++r) pw[r] = (_Float16)(sc[c][r] * dmv[c][r]);
            *reinterpret_cast<f16x4*>(&Pl[w][c16][16 * c + 4 * g]) = pw;
        }
        if (kt + 2 < NT) dm_load(kt + 2, (kt & 1) ? dmB : dmA);  // 2-tile-ahead
        // ---- PV swapped: acc = O^T frag (wave-private Pl, no barrier) ----
        f16x8 pf0 = *reinterpret_cast<const f16x8*>(&Pl[w][c16][kg]);
        f16x8 pf1 = *reinterpret_cast<const f16x8*>(&Pl[w][c16][32 + kg]);
        __builtin_amdgcn_s_setprio(1);
        #pragma unroll
        for (int dt = 0; dt < 4; ++dt) {
            f16x8 vf0 = *reinterpret_cast<const f16x8*>(&Vt[dt * 16 + c16][kg]);
            f16x8 vf1 = *reinterpret_cast<const f16x8*>(&Vt[dt * 16 + c16][32 + kg]);
            acc[dt] = __builtin_amdgcn_mfma_f32_16x16x32_f16(vf0, pf0, acc[dt], 0, 0, 0);
            acc[dt] = __builtin_amdgcn_mfma_f32_16x16x32_f16(vf1, pf1, acc[dt], 0, 0, 0);
        }
        __builtin_amdgcn_s_setprio(0);
    }

    // ---- epilogue: lane-local l_r, coalesced float4 stores ----
    float inv = DROPSCALE / l_r;
    float* orow = out + ((size_t)(b * Sn + qbase + 16 * w + c16)) * Dn + hoff;
    #pragma unroll
    for (int dt = 0; dt < 4; ++dt) {
        f32x4 o4;
        #pragma unroll
        for (int r = 0; r < 4; ++r) o4[r] = acc[dt][r] * inv;
        *reinterpret_cast<f32x4*>(orow + dt * 16 + 4 * g) = o4;
    }
}

extern "C" void kernel_launch(void* const* d_in, const int* in_sizes, int n_in,
                              void* d_out, int out_size, void* d_ws, size_t ws_size,
                              hipStream_t stream)
{
    (void)in_sizes; (void)n_in; (void)out_size; (void)d_ws; (void)ws_size;
    const float* Q   = (const float*)d_in[0];
    const float* K   = (const float*)d_in[1];
    const float* V   = (const float*)d_in[2];
    const int*   msk = (const int*)d_in[3];
    const float* dm  = (const float*)d_in[4];
    float* o = (float*)d_out;

    dim3 grid(Bn * Hn * (Sn / QB));   // 2048 blocks
    dim3 block(256);                  // 4 waves
    mha_fwd<<<grid, block, 0, stream>>>(Q, K, V, msk, dm, o);
}